// Round 15
// baseline (350.750 us; speedup 1.0000x reference)
//
#include <hip/hip_runtime.h>

#define NN 100000
#define NE 3200000
#define DD 64
#define KE 64                 // edges per worker (NE % KE == 0)
#define NW (NE / KE)          // 50000 sixteen-lane workers
#define GEMM_BLOCKS 391       // ceil(NN/256)
#define PREP_BLOCKS 12501     // ceil((NE+32)/256)

typedef unsigned int uint32;

// ---------------------------------------------------------------------------
// bf16 round-to-nearest-even of an f32 (inputs finite).
// ---------------------------------------------------------------------------
__device__ inline uint32 bf16_rne(float f) {
    uint32 u = __float_as_uint(f);
    return (u + 0x7fffu + ((u >> 16) & 1u)) >> 16;
}

// ---------------------------------------------------------------------------
// Dispatch 1: prep  ||  gemm1'  (independent work, block-range split).
// gemm1' blocks [0, GEMM_BLOCKS): xw[row,:] = bf16(x[row,:] @ W1)  (bias and
//   activation live in spmm1's flush).  One thread per row, W1 in LDS.
// prep blocks [GEMM_BLOCKS, ...): one thread per edge. Packed edge record
//   (bits 31..17 = bf16(val) sans sign, val>=0; bits 16..0 = col), rp[] span
//   fill from the sorted row stream, fused worker-start table ws[], 32 zero
//   pad records for masked batch overrun. Inline int64/int32 detection.
// ---------------------------------------------------------------------------
__global__ __launch_bounds__(256) void pre_kernel(
    const void* rowbuf, const void* colbuf, const float* __restrict__ val,
    const float* __restrict__ x, const float* __restrict__ W1,
    uint32* __restrict__ erec, int* __restrict__ rp, int* __restrict__ ws,
    uint32* __restrict__ xw) {
    __shared__ float4 sW[DD * 16];   // sW[k*16+j4] = W1[k][4j4..4j4+3]

    if (blockIdx.x < GEMM_BLOCKS) {
        for (int i = threadIdx.x; i < DD * 16; i += 256)
            sW[i] = ((const float4*)W1)[i];
        __syncthreads();

        int row = blockIdx.x * 256 + threadIdx.x;
        if (row >= NN) return;

        float acc[DD];
#pragma unroll
        for (int j = 0; j < DD; ++j) acc[j] = 0.f;

        const float4* Bp = (const float4*)(x + (size_t)row * DD);
#pragma unroll
        for (int k4 = 0; k4 < 16; ++k4) {
            float4 x4 = Bp[k4];
            float xs[4] = {x4.x, x4.y, x4.z, x4.w};
#pragma unroll
            for (int kk = 0; kk < 4; ++kk) {
                float xk = xs[kk];
                int k = 4 * k4 + kk;
#pragma unroll
                for (int j4 = 0; j4 < 16; ++j4) {
                    float4 w = sW[k * 16 + j4];
                    acc[4 * j4 + 0] = fmaf(xk, w.x, acc[4 * j4 + 0]);
                    acc[4 * j4 + 1] = fmaf(xk, w.y, acc[4 * j4 + 1]);
                    acc[4 * j4 + 2] = fmaf(xk, w.z, acc[4 * j4 + 2]);
                    acc[4 * j4 + 3] = fmaf(xk, w.w, acc[4 * j4 + 3]);
                }
            }
        }
        uint32* o = xw + (size_t)row * 32;
#pragma unroll
        for (int q = 0; q < 32; ++q)
            o[q] = bf16_rne(acc[2 * q]) | (bf16_rne(acc[2 * q + 1]) << 16);
        return;
    }

    // ---- prep branch ----
    int e = (blockIdx.x - GEMM_BLOCKS) * 256 + threadIdx.x;
    if (e >= NE + 32) return;
    if (e >= NE) { erec[e] = 0u; return; }

    const int* p32 = (const int*)rowbuf;
    bool is64 = (p32[NE / 2 + 1] == 0 && p32[NE / 2] != 0);

    int r, rn, c;
    if (is64) {
        const long long* row = (const long long*)rowbuf;
        const long long* col = (const long long*)colbuf;
        r  = (int)row[e];
        rn = (e == NE - 1) ? NN : (int)row[e + 1];
        c  = (int)col[e];
    } else {
        const int* row = (const int*)rowbuf;
        const int* col = (const int*)colbuf;
        r  = row[e];
        rn = (e == NE - 1) ? NN : row[e + 1];
        c  = col[e];
    }
    erec[e] = ((bf16_rne(val[e]) & 0x7fffu) << 17) | (uint32)c;
    for (int q = r + 1; q <= rn; ++q) rp[q] = e + 1;
    if (e == 0) {
        for (int q = 0; q <= r; ++q) rp[q] = 0;
        ws[0]  = 0;
        ws[NW] = NN;
    }
    if (((e + 1) & (KE - 1)) == 0 && (e + 1) < NE)
        ws[(e + 1) / KE] = r + 1;
}

// ---------------------------------------------------------------------------
// SpMM: r14 structure + software-pipelined erec stream. 16-lane workers with
// exclusive row ownership; lane sl holds features {4sl..4sl+3} (one uint2 =
// 128 B/row gather, 1 load per edge). 16-deep gather pipeline. The NEXT
// batch's erec word is prefetched right after this batch's gathers are
// issued, so its ~300-500 cy latency hides under the 64 ACCUM ops instead
// of heading every iteration's dependence chain. Overrun mask applied at
// use time (padding covers e0+16+sl <= NE+31). Flush adds bias (+LeakyReLU
// +bf16-pack for layer 1; f32 float4 store for layer 2), stores each row
// exactly once.
// ---------------------------------------------------------------------------
#define ISSUE(G, U, I) {                                        \
    U = (uint32)__shfl((int)rwm, (I), 16);                      \
    G = ((const uint2*)Xq)[((U & 0x1ffffu) << 4) + sl]; }

#define FLUSH() {                                                       \
    float y0 = a0 + bv.x, y1 = a1 + bv.y,                               \
          y2 = a2 + bv.z, y3 = a3 + bv.w;                               \
    if (L1) {                                                           \
        y0 = (y0 >= 0.f) ? y0 : 0.2f * y0;                              \
        y1 = (y1 >= 0.f) ? y1 : 0.2f * y1;                              \
        y2 = (y2 >= 0.f) ? y2 : 0.2f * y2;                              \
        y3 = (y3 >= 0.f) ? y3 : 0.2f * y3;                              \
        uint2 pk_;                                                      \
        pk_.x = bf16_rne(y0) | (bf16_rne(y1) << 16);                    \
        pk_.y = bf16_rne(y2) | (bf16_rne(y3) << 16);                    \
        ((uint2*)obv)[(size_t)rr * 16 + sl] = pk_;                      \
    } else {                                                            \
        float4 f4_ = make_float4(y0, y1, y2, y3);                       \
        ((float4*)obv)[(size_t)rr * 16 + sl] = f4_;                     \
    }                                                                   \
    a0 = 0.f; a1 = 0.f; a2 = 0.f; a3 = 0.f; ++rr; }

#define ACCUM(G, U, I) {                                        \
    while (e0 + (I) >= re) {                                    \
        FLUSH();                                                \
        re = (rr < r1) ? rp[rr + 1] : 0x7fffffff;               \
    }                                                           \
    float vi_ = __uint_as_float((U >> 17) << 16);               \
    a0 = fmaf(vi_, __uint_as_float(G.x << 16),          a0);    \
    a1 = fmaf(vi_, __uint_as_float(G.x & 0xffff0000u),  a1);    \
    a2 = fmaf(vi_, __uint_as_float(G.y << 16),          a2);    \
    a3 = fmaf(vi_, __uint_as_float(G.y & 0xffff0000u),  a3); }

template <bool L1>
__global__ __launch_bounds__(256, 8) void spmm_kernel(
    const uint32* __restrict__ Xq, const uint32* __restrict__ erec,
    const int* __restrict__ rp, const int* __restrict__ ws,
    const float* __restrict__ bias, void* __restrict__ obv) {
    int worker = (blockIdx.x * blockDim.x + threadIdx.x) >> 4;
    int sl = threadIdx.x & 15;
    if (worker >= NW) return;

    int rr = ws[worker];
    int r1 = ws[worker + 1];
    if (rr >= r1) return;

    const float4 bv = ((const float4*)bias)[sl];   // bias[4sl .. 4sl+3]

    int eb = rp[rr];
    int ee = rp[r1];
    int re = rp[rr + 1];
    float a0 = 0.f, a1 = 0.f, a2 = 0.f, a3 = 0.f;

    uint32 rwc = erec[eb + sl];              // batch-0 records (padded)
    for (int e0 = eb; e0 < ee; e0 += 16) {
        uint32 rwm = (e0 + sl < ee) ? rwc : 0u;   // mask overrun at use
        uint2  g0, g1, g2, g3, g4, g5, g6, g7;
        uint2  h0, h1, h2, h3, h4, h5, h6, h7;
        uint32 u0, u1, u2, u3, u4, u5, u6, u7;
        uint32 w0, w1, w2, w3, w4, w5, w6, w7;
        ISSUE(g0, u0, 0)  ISSUE(g1, u1, 1)  ISSUE(g2, u2, 2)  ISSUE(g3, u3, 3)
        ISSUE(g4, u4, 4)  ISSUE(g5, u5, 5)  ISSUE(g6, u6, 6)  ISSUE(g7, u7, 7)
        ISSUE(h0, w0, 8)  ISSUE(h1, w1, 9)  ISSUE(h2, w2, 10) ISSUE(h3, w3, 11)
        ISSUE(h4, w4, 12) ISSUE(h5, w5, 13) ISSUE(h6, w6, 14) ISSUE(h7, w7, 15)
        rwc = erec[e0 + 16 + sl];            // prefetch next batch (padded:
                                             // e0+16+sl <= ee+30 <= NE+31)
        ACCUM(g0, u0, 0)  ACCUM(g1, u1, 1)  ACCUM(g2, u2, 2)  ACCUM(g3, u3, 3)
        ACCUM(g4, u4, 4)  ACCUM(g5, u5, 5)  ACCUM(g6, u6, 6)  ACCUM(g7, u7, 7)
        ACCUM(h0, w0, 8)  ACCUM(h1, w1, 9)  ACCUM(h2, w2, 10) ACCUM(h3, w3, 11)
        ACCUM(h4, w4, 12) ACCUM(h5, w5, 13) ACCUM(h6, w6, 14) ACCUM(h7, w7, 15)
    }
    // drain: last row + trailing empty rows (bias-only rows handled too)
    while (rr < r1) { FLUSH(); }
}

// ---------------------------------------------------------------------------
// Dispatch 3: gemm2'  g[row,:] = bf16(unpack(h[row,:]) @ W2)  (bias2 lives
// in spmm2's flush).
// ---------------------------------------------------------------------------
__global__ __launch_bounds__(256) void gemm_bb_kernel(
    const uint32* __restrict__ Bb, const float* __restrict__ W,
    uint32* __restrict__ ob) {
    __shared__ float4 sW[DD * 16];
    for (int i = threadIdx.x; i < DD * 16; i += 256)
        sW[i] = ((const float4*)W)[i];
    __syncthreads();

    int row = blockIdx.x * 256 + threadIdx.x;
    if (row >= NN) return;

    float acc[DD];
#pragma unroll
    for (int j = 0; j < DD; ++j) acc[j] = 0.f;

    const uint4* Bp = (const uint4*)(Bb + (size_t)row * 32);
#pragma unroll
    for (int q4 = 0; q4 < 8; ++q4) {
        uint4 u4 = Bp[q4];
        uint32 us[4] = {u4.x, u4.y, u4.z, u4.w};
#pragma unroll
        for (int t = 0; t < 4; ++t) {
            int k = q4 * 8 + t * 2;
            float x0 = __uint_as_float(us[t] << 16);
            float x1 = __uint_as_float(us[t] & 0xffff0000u);
#pragma unroll
            for (int j4 = 0; j4 < 16; ++j4) {
                float4 w0 = sW[k * 16 + j4];
                float4 w1 = sW[(k + 1) * 16 + j4];
                acc[4 * j4 + 0] = fmaf(x0, w0.x, acc[4 * j4 + 0]);
                acc[4 * j4 + 1] = fmaf(x0, w0.y, acc[4 * j4 + 1]);
                acc[4 * j4 + 2] = fmaf(x0, w0.z, acc[4 * j4 + 2]);
                acc[4 * j4 + 3] = fmaf(x0, w0.w, acc[4 * j4 + 3]);
                acc[4 * j4 + 0] = fmaf(x1, w1.x, acc[4 * j4 + 0]);
                acc[4 * j4 + 1] = fmaf(x1, w1.y, acc[4 * j4 + 1]);
                acc[4 * j4 + 2] = fmaf(x1, w1.z, acc[4 * j4 + 2]);
                acc[4 * j4 + 3] = fmaf(x1, w1.w, acc[4 * j4 + 3]);
            }
        }
    }

    uint32* o = ob + (size_t)row * 32;
#pragma unroll
    for (int q = 0; q < 32; ++q)
        o[q] = bf16_rne(acc[2 * q]) | (bf16_rne(acc[2 * q + 1]) << 16);
}

// ---------------------------------------------------------------------------
extern "C" void kernel_launch(void* const* d_in, const int* in_sizes, int n_in,
                              void* d_out, int out_size, void* d_ws, size_t ws_size,
                              hipStream_t stream) {
    const float* x       = (const float*)d_in[0];
    const void*  adj_row = d_in[1];
    const void*  adj_col = d_in[2];
    const float* adj_val = (const float*)d_in[3];
    const float* W1      = (const float*)d_in[4];
    const float* b1      = (const float*)d_in[5];
    const float* W2      = (const float*)d_in[6];
    const float* b2      = (const float*)d_in[7];
    float*       out     = (float*)d_out;

    // ws: bufA(h) [NN*32 u32] | bufB(xW1/hW2) [NN*32 u32] | erec | rp | ws
    uint32* bufA = (uint32*)d_ws;
    uint32* bufB = bufA + (size_t)NN * 32;
    uint32* erec = bufB + (size_t)NN * 32;
    int*    rp   = (int*)(erec + NE + 32);
    int*    wst  = rp + (NN + 1);

    const int spmm_blocks = (NW * 16) / 256;   // 3125

    // 1. prep || gemm1' : erec/rp/ws + bufB = bf16(x W1)
    pre_kernel<<<GEMM_BLOCKS + PREP_BLOCKS, 256, 0, stream>>>(
        adj_row, adj_col, adj_val, x, W1, erec, rp, wst, bufB);

    // 2. spmm1: bufA = bf16(LReLU(A bufB + b1))
    spmm_kernel<true><<<spmm_blocks, 256, 0, stream>>>(bufB, erec, rp, wst,
                                                       b1, bufA);

    // 3. gemm2': bufB = bf16(bufA W2)
    gemm_bb_kernel<<<GEMM_BLOCKS, 256, 0, stream>>>(bufA, W2, bufB);

    // 4. spmm2: out = A bufB + b2   (f32, float4 stores)
    spmm_kernel<false><<<spmm_blocks, 256, 0, stream>>>(bufB, erec, rp, wst,
                                                        b2, out);
}

// Round 16
// 209.597 us; speedup vs baseline: 1.6735x; 1.6735x over previous
//
#include <hip/hip_runtime.h>

#define NN 100000
#define NE 3200000
#define DD 64
#define KE 64                 // edges per worker (NE % KE == 0)
#define NW (NE / KE)          // 50000 sixteen-lane workers
#define GEMM_BLOCKS 391       // ceil(NN/256)
#define PREP_BLOCKS 12501     // ceil((NE+32)/256)

typedef unsigned int uint32;

// ---------------------------------------------------------------------------
// bf16 round-to-nearest-even of an f32 (inputs finite).
// ---------------------------------------------------------------------------
__device__ inline uint32 bf16_rne(float f) {
    uint32 u = __float_as_uint(f);
    return (u + 0x7fffu + ((u >> 16) & 1u)) >> 16;
}

// ---------------------------------------------------------------------------
// Dispatch 1: prep  ||  gemm1'  (independent work, block-range split).
// gemm1' blocks [0, GEMM_BLOCKS): xw[row,:] = bf16(x[row,:] @ W1)  (bias and
//   activation live in spmm1's flush).  One thread per row, W1 in LDS.
// prep blocks [GEMM_BLOCKS, ...): one thread per edge. Packed edge record
//   (bits 31..17 = bf16(val) sans sign, val>=0; bits 16..0 = col), rp[] span
//   fill from the sorted row stream, fused worker-start table ws[], 32 zero
//   pad records for masked batch overrun. Inline int64/int32 detection.
// ---------------------------------------------------------------------------
__global__ __launch_bounds__(256) void pre_kernel(
    const void* rowbuf, const void* colbuf, const float* __restrict__ val,
    const float* __restrict__ x, const float* __restrict__ W1,
    uint32* __restrict__ erec, int* __restrict__ rp, int* __restrict__ ws,
    uint32* __restrict__ xw) {
    __shared__ float4 sW[DD * 16];   // sW[k*16+j4] = W1[k][4j4..4j4+3]

    if (blockIdx.x < GEMM_BLOCKS) {
        for (int i = threadIdx.x; i < DD * 16; i += 256)
            sW[i] = ((const float4*)W1)[i];
        __syncthreads();

        int row = blockIdx.x * 256 + threadIdx.x;
        if (row >= NN) return;

        float acc[DD];
#pragma unroll
        for (int j = 0; j < DD; ++j) acc[j] = 0.f;

        const float4* Bp = (const float4*)(x + (size_t)row * DD);
#pragma unroll
        for (int k4 = 0; k4 < 16; ++k4) {
            float4 x4 = Bp[k4];
            float xs[4] = {x4.x, x4.y, x4.z, x4.w};
#pragma unroll
            for (int kk = 0; kk < 4; ++kk) {
                float xk = xs[kk];
                int k = 4 * k4 + kk;
#pragma unroll
                for (int j4 = 0; j4 < 16; ++j4) {
                    float4 w = sW[k * 16 + j4];
                    acc[4 * j4 + 0] = fmaf(xk, w.x, acc[4 * j4 + 0]);
                    acc[4 * j4 + 1] = fmaf(xk, w.y, acc[4 * j4 + 1]);
                    acc[4 * j4 + 2] = fmaf(xk, w.z, acc[4 * j4 + 2]);
                    acc[4 * j4 + 3] = fmaf(xk, w.w, acc[4 * j4 + 3]);
                }
            }
        }
        uint32* o = xw + (size_t)row * 32;
#pragma unroll
        for (int q = 0; q < 32; ++q)
            o[q] = bf16_rne(acc[2 * q]) | (bf16_rne(acc[2 * q + 1]) << 16);
        return;
    }

    // ---- prep branch ----
    int e = (blockIdx.x - GEMM_BLOCKS) * 256 + threadIdx.x;
    if (e >= NE + 32) return;
    if (e >= NE) { erec[e] = 0u; return; }

    const int* p32 = (const int*)rowbuf;
    bool is64 = (p32[NE / 2 + 1] == 0 && p32[NE / 2] != 0);

    int r, rn, c;
    if (is64) {
        const long long* row = (const long long*)rowbuf;
        const long long* col = (const long long*)colbuf;
        r  = (int)row[e];
        rn = (e == NE - 1) ? NN : (int)row[e + 1];
        c  = (int)col[e];
    } else {
        const int* row = (const int*)rowbuf;
        const int* col = (const int*)colbuf;
        r  = row[e];
        rn = (e == NE - 1) ? NN : row[e + 1];
        c  = col[e];
    }
    erec[e] = ((bf16_rne(val[e]) & 0x7fffu) << 17) | (uint32)c;
    for (int q = r + 1; q <= rn; ++q) rp[q] = e + 1;
    if (e == 0) {
        for (int q = 0; q <= r; ++q) rp[q] = 0;
        ws[0]  = 0;
        ws[NW] = NN;
    }
    if (((e + 1) & (KE - 1)) == 0 && (e + 1) < NE)
        ws[(e + 1) / KE] = r + 1;
}

// ---------------------------------------------------------------------------
// SpMM: r14 structure + software-pipelined erec stream (and NO min-waves
// launch bound -- round 15's (256,8) squeezed VGPR 48->32 and spilled the
// gather pipeline to scratch: WRITE 12.5->241 MB, 2.2x slower. Occupancy
// was never the binding constraint; registers are).
// 16-lane workers with exclusive row ownership; lane sl holds features
// {4sl..4sl+3} (one uint2 = 128 B/row gather, 1 load per edge). 16-deep
// gather pipeline. The NEXT batch's erec word is prefetched right after
// this batch's gathers are issued, hiding its latency under the 64 ACCUMs.
// Overrun mask applied at use time (padding covers e0+16+sl <= NE+31).
// Flush adds bias (+LeakyReLU+bf16-pack for layer 1; f32 float4 store for
// layer 2), stores each row exactly once.
// ---------------------------------------------------------------------------
#define ISSUE(G, U, I) {                                        \
    U = (uint32)__shfl((int)rwm, (I), 16);                      \
    G = ((const uint2*)Xq)[((U & 0x1ffffu) << 4) + sl]; }

#define FLUSH() {                                                       \
    float y0 = a0 + bv.x, y1 = a1 + bv.y,                               \
          y2 = a2 + bv.z, y3 = a3 + bv.w;                               \
    if (L1) {                                                           \
        y0 = (y0 >= 0.f) ? y0 : 0.2f * y0;                              \
        y1 = (y1 >= 0.f) ? y1 : 0.2f * y1;                              \
        y2 = (y2 >= 0.f) ? y2 : 0.2f * y2;                              \
        y3 = (y3 >= 0.f) ? y3 : 0.2f * y3;                              \
        uint2 pk_;                                                      \
        pk_.x = bf16_rne(y0) | (bf16_rne(y1) << 16);                    \
        pk_.y = bf16_rne(y2) | (bf16_rne(y3) << 16);                    \
        ((uint2*)obv)[(size_t)rr * 16 + sl] = pk_;                      \
    } else {                                                            \
        float4 f4_ = make_float4(y0, y1, y2, y3);                       \
        ((float4*)obv)[(size_t)rr * 16 + sl] = f4_;                     \
    }                                                                   \
    a0 = 0.f; a1 = 0.f; a2 = 0.f; a3 = 0.f; ++rr; }

#define ACCUM(G, U, I) {                                        \
    while (e0 + (I) >= re) {                                    \
        FLUSH();                                                \
        re = (rr < r1) ? rp[rr + 1] : 0x7fffffff;               \
    }                                                           \
    float vi_ = __uint_as_float((U >> 17) << 16);               \
    a0 = fmaf(vi_, __uint_as_float(G.x << 16),          a0);    \
    a1 = fmaf(vi_, __uint_as_float(G.x & 0xffff0000u),  a1);    \
    a2 = fmaf(vi_, __uint_as_float(G.y << 16),          a2);    \
    a3 = fmaf(vi_, __uint_as_float(G.y & 0xffff0000u),  a3); }

template <bool L1>
__global__ __launch_bounds__(256) void spmm_kernel(
    const uint32* __restrict__ Xq, const uint32* __restrict__ erec,
    const int* __restrict__ rp, const int* __restrict__ ws,
    const float* __restrict__ bias, void* __restrict__ obv) {
    int worker = (blockIdx.x * blockDim.x + threadIdx.x) >> 4;
    int sl = threadIdx.x & 15;
    if (worker >= NW) return;

    int rr = ws[worker];
    int r1 = ws[worker + 1];
    if (rr >= r1) return;

    const float4 bv = ((const float4*)bias)[sl];   // bias[4sl .. 4sl+3]

    int eb = rp[rr];
    int ee = rp[r1];
    int re = rp[rr + 1];
    float a0 = 0.f, a1 = 0.f, a2 = 0.f, a3 = 0.f;

    uint32 rwc = erec[eb + sl];              // batch-0 records (padded)
    for (int e0 = eb; e0 < ee; e0 += 16) {
        uint32 rwm = (e0 + sl < ee) ? rwc : 0u;   // mask overrun at use
        uint2  g0, g1, g2, g3, g4, g5, g6, g7;
        uint2  h0, h1, h2, h3, h4, h5, h6, h7;
        uint32 u0, u1, u2, u3, u4, u5, u6, u7;
        uint32 w0, w1, w2, w3, w4, w5, w6, w7;
        ISSUE(g0, u0, 0)  ISSUE(g1, u1, 1)  ISSUE(g2, u2, 2)  ISSUE(g3, u3, 3)
        ISSUE(g4, u4, 4)  ISSUE(g5, u5, 5)  ISSUE(g6, u6, 6)  ISSUE(g7, u7, 7)
        ISSUE(h0, w0, 8)  ISSUE(h1, w1, 9)  ISSUE(h2, w2, 10) ISSUE(h3, w3, 11)
        ISSUE(h4, w4, 12) ISSUE(h5, w5, 13) ISSUE(h6, w6, 14) ISSUE(h7, w7, 15)
        rwc = erec[e0 + 16 + sl];            // prefetch next batch (padded:
                                             // e0+16+sl <= ee+30 <= NE+31)
        ACCUM(g0, u0, 0)  ACCUM(g1, u1, 1)  ACCUM(g2, u2, 2)  ACCUM(g3, u3, 3)
        ACCUM(g4, u4, 4)  ACCUM(g5, u5, 5)  ACCUM(g6, u6, 6)  ACCUM(g7, u7, 7)
        ACCUM(h0, w0, 8)  ACCUM(h1, w1, 9)  ACCUM(h2, w2, 10) ACCUM(h3, w3, 11)
        ACCUM(h4, w4, 12) ACCUM(h5, w5, 13) ACCUM(h6, w6, 14) ACCUM(h7, w7, 15)
    }
    // drain: last row + trailing empty rows (bias-only rows handled too)
    while (rr < r1) { FLUSH(); }
}

// ---------------------------------------------------------------------------
// Dispatch 3: gemm2'  g[row,:] = bf16(unpack(h[row,:]) @ W2)  (bias2 lives
// in spmm2's flush).
// ---------------------------------------------------------------------------
__global__ __launch_bounds__(256) void gemm_bb_kernel(
    const uint32* __restrict__ Bb, const float* __restrict__ W,
    uint32* __restrict__ ob) {
    __shared__ float4 sW[DD * 16];
    for (int i = threadIdx.x; i < DD * 16; i += 256)
        sW[i] = ((const float4*)W)[i];
    __syncthreads();

    int row = blockIdx.x * 256 + threadIdx.x;
    if (row >= NN) return;

    float acc[DD];
#pragma unroll
    for (int j = 0; j < DD; ++j) acc[j] = 0.f;

    const uint4* Bp = (const uint4*)(Bb + (size_t)row * 32);
#pragma unroll
    for (int q4 = 0; q4 < 8; ++q4) {
        uint4 u4 = Bp[q4];
        uint32 us[4] = {u4.x, u4.y, u4.z, u4.w};
#pragma unroll
        for (int t = 0; t < 4; ++t) {
            int k = q4 * 8 + t * 2;
            float x0 = __uint_as_float(us[t] << 16);
            float x1 = __uint_as_float(us[t] & 0xffff0000u);
#pragma unroll
            for (int j4 = 0; j4 < 16; ++j4) {
                float4 w0 = sW[k * 16 + j4];
                float4 w1 = sW[(k + 1) * 16 + j4];
                acc[4 * j4 + 0] = fmaf(x0, w0.x, acc[4 * j4 + 0]);
                acc[4 * j4 + 1] = fmaf(x0, w0.y, acc[4 * j4 + 1]);
                acc[4 * j4 + 2] = fmaf(x0, w0.z, acc[4 * j4 + 2]);
                acc[4 * j4 + 3] = fmaf(x0, w0.w, acc[4 * j4 + 3]);
                acc[4 * j4 + 0] = fmaf(x1, w1.x, acc[4 * j4 + 0]);
                acc[4 * j4 + 1] = fmaf(x1, w1.y, acc[4 * j4 + 1]);
                acc[4 * j4 + 2] = fmaf(x1, w1.z, acc[4 * j4 + 2]);
                acc[4 * j4 + 3] = fmaf(x1, w1.w, acc[4 * j4 + 3]);
            }
        }
    }

    uint32* o = ob + (size_t)row * 32;
#pragma unroll
    for (int q = 0; q < 32; ++q)
        o[q] = bf16_rne(acc[2 * q]) | (bf16_rne(acc[2 * q + 1]) << 16);
}

// ---------------------------------------------------------------------------
extern "C" void kernel_launch(void* const* d_in, const int* in_sizes, int n_in,
                              void* d_out, int out_size, void* d_ws, size_t ws_size,
                              hipStream_t stream) {
    const float* x       = (const float*)d_in[0];
    const void*  adj_row = d_in[1];
    const void*  adj_col = d_in[2];
    const float* adj_val = (const float*)d_in[3];
    const float* W1      = (const float*)d_in[4];
    const float* b1      = (const float*)d_in[5];
    const float* W2      = (const float*)d_in[6];
    const float* b2      = (const float*)d_in[7];
    float*       out     = (float*)d_out;

    // ws: bufA(h) [NN*32 u32] | bufB(xW1/hW2) [NN*32 u32] | erec | rp | ws
    uint32* bufA = (uint32*)d_ws;
    uint32* bufB = bufA + (size_t)NN * 32;
    uint32* erec = bufB + (size_t)NN * 32;
    int*    rp   = (int*)(erec + NE + 32);
    int*    wst  = rp + (NN + 1);

    const int spmm_blocks = (NW * 16) / 256;   // 3125

    // 1. prep || gemm1' : erec/rp/ws + bufB = bf16(x W1)
    pre_kernel<<<GEMM_BLOCKS + PREP_BLOCKS, 256, 0, stream>>>(
        adj_row, adj_col, adj_val, x, W1, erec, rp, wst, bufB);

    // 2. spmm1: bufA = bf16(LReLU(A bufB + b1))
    spmm_kernel<true><<<spmm_blocks, 256, 0, stream>>>(bufB, erec, rp, wst,
                                                       b1, bufA);

    // 3. gemm2': bufB = bf16(bufA W2)
    gemm_bb_kernel<<<GEMM_BLOCKS, 256, 0, stream>>>(bufA, W2, bufB);

    // 4. spmm2: out = A bufB + b2   (f32, float4 stores)
    spmm_kernel<false><<<spmm_blocks, 256, 0, stream>>>(bufB, erec, rp, wst,
                                                        b2, out);
}

// Round 17
// 185.821 us; speedup vs baseline: 1.8876x; 1.1280x over previous
//
#include <hip/hip_runtime.h>

#define NN 100000
#define NE 3200000
#define DD 64
#define KE 64                 // edges per worker (NE % KE == 0)
#define NW (NE / KE)          // 50000 sixteen-lane workers
#define GEMM_BLOCKS 391       // ceil(NN/256)
#define PREP_BLOCKS 12501     // ceil((NE+32)/256)

typedef unsigned int uint32;

// ---------------------------------------------------------------------------
// bf16 round-to-nearest-even of an f32 (inputs finite).
// ---------------------------------------------------------------------------
__device__ inline uint32 bf16_rne(float f) {
    uint32 u = __float_as_uint(f);
    return (u + 0x7fffu + ((u >> 16) & 1u)) >> 16;
}

// ---------------------------------------------------------------------------
// Quantize one 64-feature f32 row to SIGNED int8 with per-row scale:
// q[j] = rint(acc[j] * 127/max|acc|) in [-127,127]; sc = max|acc|/127.
// Dequant in spmm is exact-linear: acc_j = sum_e (val[e]*sc[c]) * q_j
// (signed -> no bias correction anywhere).
// ---------------------------------------------------------------------------
__device__ inline void quant_store_s8(const float* acc,
                                      uint32* __restrict__ qrow,
                                      float* __restrict__ scp) {
    float m = 0.f;
#pragma unroll
    for (int j = 0; j < DD; ++j) m = fmaxf(m, fabsf(acc[j]));
    float inv = (m > 0.f) ? (127.f / m) : 0.f;
    *scp = m * (1.f / 127.f);
#pragma unroll
    for (int q = 0; q < 16; ++q) {
        uint32 p = 0;
#pragma unroll
        for (int b = 0; b < 4; ++b) {
            int v = (int)rintf(acc[4 * q + b] * inv);
            p |= ((uint32)(v & 0xff)) << (8 * b);
        }
        qrow[q] = p;
    }
}

// ---------------------------------------------------------------------------
// Dispatch 1: prep  ||  gemm1'  (independent work, block-range split).
// gemm1' blocks [0, GEMM_BLOCKS): qt[row,:], sc[row] = quant_s8(x[row,:] @ W1)
//   (bias and activation live in spmm1's flush). One thread per row, W1 in
//   LDS (uniform-address float4 broadcast).
// prep blocks [GEMM_BLOCKS, ...): one thread per edge. Packed edge record
//   (bits 31..17 = bf16(val) sans sign, val>=0; bits 16..0 = col), rp[] span
//   fill from the sorted row stream, fused worker-start table ws[], 32 zero
//   pad records for masked batch overrun. Inline int64/int32 detection.
// ---------------------------------------------------------------------------
__global__ __launch_bounds__(256) void pre_kernel(
    const void* rowbuf, const void* colbuf, const float* __restrict__ val,
    const float* __restrict__ x, const float* __restrict__ W1,
    uint32* __restrict__ erec, int* __restrict__ rp, int* __restrict__ ws,
    uint32* __restrict__ qt, float* __restrict__ sc) {
    __shared__ float4 sW[DD * 16];   // sW[k*16+j4] = W1[k][4j4..4j4+3]

    if (blockIdx.x < GEMM_BLOCKS) {
        for (int i = threadIdx.x; i < DD * 16; i += 256)
            sW[i] = ((const float4*)W1)[i];
        __syncthreads();

        int row = blockIdx.x * 256 + threadIdx.x;
        if (row >= NN) return;

        float acc[DD];
#pragma unroll
        for (int j = 0; j < DD; ++j) acc[j] = 0.f;

        const float4* Bp = (const float4*)(x + (size_t)row * DD);
#pragma unroll
        for (int k4 = 0; k4 < 16; ++k4) {
            float4 x4 = Bp[k4];
            float xs[4] = {x4.x, x4.y, x4.z, x4.w};
#pragma unroll
            for (int kk = 0; kk < 4; ++kk) {
                float xk = xs[kk];
                int k = 4 * k4 + kk;
#pragma unroll
                for (int j4 = 0; j4 < 16; ++j4) {
                    float4 w = sW[k * 16 + j4];
                    acc[4 * j4 + 0] = fmaf(xk, w.x, acc[4 * j4 + 0]);
                    acc[4 * j4 + 1] = fmaf(xk, w.y, acc[4 * j4 + 1]);
                    acc[4 * j4 + 2] = fmaf(xk, w.z, acc[4 * j4 + 2]);
                    acc[4 * j4 + 3] = fmaf(xk, w.w, acc[4 * j4 + 3]);
                }
            }
        }
        quant_store_s8(acc, qt + (size_t)row * 16, sc + row);
        return;
    }

    // ---- prep branch ----
    int e = (blockIdx.x - GEMM_BLOCKS) * 256 + threadIdx.x;
    if (e >= NE + 32) return;
    if (e >= NE) { erec[e] = 0u; return; }

    const int* p32 = (const int*)rowbuf;
    bool is64 = (p32[NE / 2 + 1] == 0 && p32[NE / 2] != 0);

    int r, rn, c;
    if (is64) {
        const long long* row = (const long long*)rowbuf;
        const long long* col = (const long long*)colbuf;
        r  = (int)row[e];
        rn = (e == NE - 1) ? NN : (int)row[e + 1];
        c  = (int)col[e];
    } else {
        const int* row = (const int*)rowbuf;
        const int* col = (const int*)colbuf;
        r  = row[e];
        rn = (e == NE - 1) ? NN : row[e + 1];
        c  = col[e];
    }
    erec[e] = ((bf16_rne(val[e]) & 0x7fffu) << 17) | (uint32)c;
    for (int q = r + 1; q <= rn; ++q) rp[q] = e + 1;
    if (e == 0) {
        for (int q = 0; q <= r; ++q) rp[q] = 0;
        ws[0]  = 0;
        ws[NW] = NN;
    }
    if (((e + 1) & (KE - 1)) == 0 && (e + 1) < NE)
        ws[(e + 1) / KE] = r + 1;
}

// ---------------------------------------------------------------------------
// SpMM on the signed-int8 table. r16's frame: 16-lane workers, exclusive row
// ownership, 16-deep gather pipeline, software-pipelined erec stream, no
// min-waves clause (r15 lesson: register squeeze -> scratch spill).
// Lane sl holds features {4sl..4sl+3} = one uint of 4 signed bytes (64 B/row
// gather = ONE cache line per edge, vs r16's two). Slot = {G uint, S float}
// = 2 regs, same budget as r16's uint2. ACCUM: t = val*sc[c]; 4 sext-byte
// FMAs; no bias correction (signed quant). Flush adds bias (+LeakyReLU+
// bf16-pack for layer 1; f32 float4 store for layer 2), each row exactly
// once. Overrun edges masked to record 0 (row 0, val 0: one hot line).
// ---------------------------------------------------------------------------
#define ISSUE(G, S, I) {                                        \
    uint32 u_ = (uint32)__shfl((int)rwm, (I), 16);              \
    uint32 c_ = u_ & 0x1ffffu;                                  \
    G = qt[((size_t)c_ << 4) + (uint32)sl];                     \
    S = sc[c_]; }

#define FLUSH() {                                                       \
    float y0 = a0 + bv.x, y1 = a1 + bv.y,                               \
          y2 = a2 + bv.z, y3 = a3 + bv.w;                               \
    if (L1) {                                                           \
        y0 = (y0 >= 0.f) ? y0 : 0.2f * y0;                              \
        y1 = (y1 >= 0.f) ? y1 : 0.2f * y1;                              \
        y2 = (y2 >= 0.f) ? y2 : 0.2f * y2;                              \
        y3 = (y3 >= 0.f) ? y3 : 0.2f * y3;                              \
        uint2 pk_;                                                      \
        pk_.x = bf16_rne(y0) | (bf16_rne(y1) << 16);                    \
        pk_.y = bf16_rne(y2) | (bf16_rne(y3) << 16);                    \
        ((uint2*)obv)[(size_t)rr * 16 + sl] = pk_;                      \
    } else {                                                            \
        float4 f4_ = make_float4(y0, y1, y2, y3);                       \
        ((float4*)obv)[(size_t)rr * 16 + sl] = f4_;                     \
    }                                                                   \
    a0 = 0.f; a1 = 0.f; a2 = 0.f; a3 = 0.f; ++rr; }

#define ACCUM(G, S, I) {                                        \
    while (e0 + (I) >= re) {                                    \
        FLUSH();                                                \
        re = (rr < r1) ? rp[rr + 1] : 0x7fffffff;               \
    }                                                           \
    uint32 u_ = (uint32)__shfl((int)rwm, (I), 16);              \
    float t_ = __uint_as_float((u_ >> 17) << 16) * S;           \
    a0 = fmaf(t_, (float)((int)(G << 24) >> 24), a0);           \
    a1 = fmaf(t_, (float)((int)(G << 16) >> 24), a1);           \
    a2 = fmaf(t_, (float)((int)(G <<  8) >> 24), a2);           \
    a3 = fmaf(t_, (float)((int)G         >> 24), a3); }

template <bool L1>
__global__ __launch_bounds__(256) void spmm_kernel(
    const uint32* __restrict__ qt, const float* __restrict__ sc,
    const uint32* __restrict__ erec, const int* __restrict__ rp,
    const int* __restrict__ ws, const float* __restrict__ bias,
    void* __restrict__ obv) {
    int worker = (blockIdx.x * blockDim.x + threadIdx.x) >> 4;
    int sl = threadIdx.x & 15;
    if (worker >= NW) return;

    int rr = ws[worker];
    int r1 = ws[worker + 1];
    if (rr >= r1) return;

    const float4 bv = ((const float4*)bias)[sl];   // bias[4sl .. 4sl+3]

    int eb = rp[rr];
    int ee = rp[r1];
    int re = rp[rr + 1];
    float a0 = 0.f, a1 = 0.f, a2 = 0.f, a3 = 0.f;

    uint32 rwc = erec[eb + sl];              // batch-0 records (padded)
    for (int e0 = eb; e0 < ee; e0 += 16) {
        uint32 rwm = (e0 + sl < ee) ? rwc : 0u;   // mask overrun at use
        uint32 g0, g1, g2, g3, g4, g5, g6, g7;
        uint32 h0, h1, h2, h3, h4, h5, h6, h7;
        float  s0, s1, s2, s3, s4, s5, s6, s7;
        float  t0, t1, t2, t3, t4, t5, t6, t7;
        ISSUE(g0, s0, 0)  ISSUE(g1, s1, 1)  ISSUE(g2, s2, 2)  ISSUE(g3, s3, 3)
        ISSUE(g4, s4, 4)  ISSUE(g5, s5, 5)  ISSUE(g6, s6, 6)  ISSUE(g7, s7, 7)
        ISSUE(h0, t0, 8)  ISSUE(h1, t1, 9)  ISSUE(h2, t2, 10) ISSUE(h3, t3, 11)
        ISSUE(h4, t4, 12) ISSUE(h5, t5, 13) ISSUE(h6, t6, 14) ISSUE(h7, t7, 15)
        rwc = erec[e0 + 16 + sl];            // prefetch next batch (padded:
                                             // e0+16+sl <= ee+30 <= NE+31)
        ACCUM(g0, s0, 0)  ACCUM(g1, s1, 1)  ACCUM(g2, s2, 2)  ACCUM(g3, s3, 3)
        ACCUM(g4, s4, 4)  ACCUM(g5, s5, 5)  ACCUM(g6, s6, 6)  ACCUM(g7, s7, 7)
        ACCUM(h0, t0, 8)  ACCUM(h1, t1, 9)  ACCUM(h2, t2, 10) ACCUM(h3, t3, 11)
        ACCUM(h4, t4, 12) ACCUM(h5, t5, 13) ACCUM(h6, t6, 14) ACCUM(h7, t7, 15)
    }
    // drain: last row + trailing empty rows (bias-only rows handled too)
    while (rr < r1) { FLUSH(); }
}

// ---------------------------------------------------------------------------
// Dispatch 3: gemm2'  qt[row,:], sc[row] = quant_s8(unpack_bf16(h[row,:])@W2)
// (bias2 lives in spmm2's flush).
// ---------------------------------------------------------------------------
__global__ __launch_bounds__(256) void gemm_bb_kernel(
    const uint32* __restrict__ Bb, const float* __restrict__ W,
    uint32* __restrict__ qt, float* __restrict__ sc) {
    __shared__ float4 sW[DD * 16];
    for (int i = threadIdx.x; i < DD * 16; i += 256)
        sW[i] = ((const float4*)W)[i];
    __syncthreads();

    int row = blockIdx.x * 256 + threadIdx.x;
    if (row >= NN) return;

    float acc[DD];
#pragma unroll
    for (int j = 0; j < DD; ++j) acc[j] = 0.f;

    const uint4* Bp = (const uint4*)(Bb + (size_t)row * 32);
#pragma unroll
    for (int q4 = 0; q4 < 8; ++q4) {
        uint4 u4 = Bp[q4];
        uint32 us[4] = {u4.x, u4.y, u4.z, u4.w};
#pragma unroll
        for (int t = 0; t < 4; ++t) {
            int k = q4 * 8 + t * 2;
            float x0 = __uint_as_float(us[t] << 16);
            float x1 = __uint_as_float(us[t] & 0xffff0000u);
#pragma unroll
            for (int j4 = 0; j4 < 16; ++j4) {
                float4 w0 = sW[k * 16 + j4];
                float4 w1 = sW[(k + 1) * 16 + j4];
                acc[4 * j4 + 0] = fmaf(x0, w0.x, acc[4 * j4 + 0]);
                acc[4 * j4 + 1] = fmaf(x0, w0.y, acc[4 * j4 + 1]);
                acc[4 * j4 + 2] = fmaf(x0, w0.z, acc[4 * j4 + 2]);
                acc[4 * j4 + 3] = fmaf(x0, w0.w, acc[4 * j4 + 3]);
                acc[4 * j4 + 0] = fmaf(x1, w1.x, acc[4 * j4 + 0]);
                acc[4 * j4 + 1] = fmaf(x1, w1.y, acc[4 * j4 + 1]);
                acc[4 * j4 + 2] = fmaf(x1, w1.z, acc[4 * j4 + 2]);
                acc[4 * j4 + 3] = fmaf(x1, w1.w, acc[4 * j4 + 3]);
            }
        }
    }
    quant_store_s8(acc, qt + (size_t)row * 16, sc + row);
}

// ---------------------------------------------------------------------------
extern "C" void kernel_launch(void* const* d_in, const int* in_sizes, int n_in,
                              void* d_out, int out_size, void* d_ws, size_t ws_size,
                              hipStream_t stream) {
    const float* x       = (const float*)d_in[0];
    const void*  adj_row = d_in[1];
    const void*  adj_col = d_in[2];
    const float* adj_val = (const float*)d_in[3];
    const float* W1      = (const float*)d_in[4];
    const float* b1      = (const float*)d_in[5];
    const float* W2      = (const float*)d_in[6];
    const float* b2      = (const float*)d_in[7];
    float*       out     = (float*)d_out;

    // ws: bufA(h bf16) [NN*32 u32] | qt [NN*16 u32] | sc [NN f32] | erec | rp | ws
    uint32* bufA = (uint32*)d_ws;
    uint32* qt   = bufA + (size_t)NN * 32;
    float*  sc   = (float*)(qt + (size_t)NN * 16);
    uint32* erec = (uint32*)(sc + NN);
    int*    rp   = (int*)(erec + NE + 32);
    int*    wst  = rp + (NN + 1);

    const int spmm_blocks = (NW * 16) / 256;   // 3125

    // 1. prep || gemm1' : erec/rp/ws + qt,sc = quant_s8(x W1)
    pre_kernel<<<GEMM_BLOCKS + PREP_BLOCKS, 256, 0, stream>>>(
        adj_row, adj_col, adj_val, x, W1, erec, rp, wst, qt, sc);

    // 2. spmm1: bufA = bf16(LReLU(A dequant(qt) + b1))
    spmm_kernel<true><<<spmm_blocks, 256, 0, stream>>>(qt, sc, erec, rp, wst,
                                                       b1, bufA);

    // 3. gemm2': qt,sc = quant_s8(bufA W2)
    gemm_bb_kernel<<<GEMM_BLOCKS, 256, 0, stream>>>(bufA, W2, qt, sc);

    // 4. spmm2: out = A dequant(qt) + b2   (f32, float4 stores)
    spmm_kernel<false><<<spmm_blocks, 256, 0, stream>>>(qt, sc, erec, rp, wst,
                                                        b2, out);
}

// Round 18
// 180.439 us; speedup vs baseline: 1.9439x; 1.0298x over previous
//
#include <hip/hip_runtime.h>

#define NN 100000
#define NE 3200000
#define DD 64
#define KE 64                 // edges per worker (NE % KE == 0)
#define NW (NE / KE)          // 50000 sixteen-lane workers
#define GEMM_BLOCKS 391       // ceil(NN/256)
#define PREP_BLOCKS 12501     // ceil((NE+32)/256)

typedef unsigned int uint32;

// ---------------------------------------------------------------------------
// bf16 round-to-nearest-even of an f32 (inputs finite).
// ---------------------------------------------------------------------------
__device__ inline uint32 bf16_rne(float f) {
    uint32 u = __float_as_uint(f);
    return (u + 0x7fffu + ((u >> 16) & 1u)) >> 16;
}

// ---------------------------------------------------------------------------
// Quantize one 64-feature f32 row to BIASED uint8 with per-row scale:
// q[j] = rint(acc[j] * 127/max|acc|) + 128 in [1,255]; sc = max|acc|/127.
// Dequant in spmm: acc_j = sum_e t_e*q_j - 128*sum_e t_e  (t_e = val*sc[c];
// correction exact, applied at flush). Unsigned bytes unpack with single
// v_cvt_f32_ubyte{0..3} ops (vs bfe+cvt for signed).
// ---------------------------------------------------------------------------
__device__ inline void quant_store_u8(const float* acc,
                                      uint32* __restrict__ qrow,
                                      float* __restrict__ scp) {
    float m = 0.f;
#pragma unroll
    for (int j = 0; j < DD; ++j) m = fmaxf(m, fabsf(acc[j]));
    float inv = (m > 0.f) ? (127.f / m) : 0.f;
    *scp = m * (1.f / 127.f);
#pragma unroll
    for (int q = 0; q < 16; ++q) {
        uint32 p = 0;
#pragma unroll
        for (int b = 0; b < 4; ++b) {
            int v = (int)rintf(acc[4 * q + b] * inv) + 128;
            p |= ((uint32)v) << (8 * b);
        }
        qrow[q] = p;
    }
}

// ---------------------------------------------------------------------------
// Dispatch 1: prep  ||  gemm1'  (independent work, block-range split).
// gemm1' blocks [0, GEMM_BLOCKS): qt[row,:], sc[row] = quant_u8(x[row,:] @ W1)
//   (bias and activation live in spmm1's flush). One thread per row, W1 in
//   LDS (uniform-address float4 broadcast).
// prep blocks [GEMM_BLOCKS, ...): one thread per edge. Packed edge record
//   (bits 31..17 = bf16(val) sans sign, val>=0; bits 16..0 = col), rp[] span
//   fill from the sorted row stream, fused worker-start table ws[], 32 zero
//   pad records for masked batch overrun. Inline int64/int32 detection.
// ---------------------------------------------------------------------------
__global__ __launch_bounds__(256) void pre_kernel(
    const void* rowbuf, const void* colbuf, const float* __restrict__ val,
    const float* __restrict__ x, const float* __restrict__ W1,
    uint32* __restrict__ erec, int* __restrict__ rp, int* __restrict__ ws,
    uint32* __restrict__ qt, float* __restrict__ sc) {
    __shared__ float4 sW[DD * 16];   // sW[k*16+j4] = W1[k][4j4..4j4+3]

    if (blockIdx.x < GEMM_BLOCKS) {
        for (int i = threadIdx.x; i < DD * 16; i += 256)
            sW[i] = ((const float4*)W1)[i];
        __syncthreads();

        int row = blockIdx.x * 256 + threadIdx.x;
        if (row >= NN) return;

        float acc[DD];
#pragma unroll
        for (int j = 0; j < DD; ++j) acc[j] = 0.f;

        const float4* Bp = (const float4*)(x + (size_t)row * DD);
#pragma unroll
        for (int k4 = 0; k4 < 16; ++k4) {
            float4 x4 = Bp[k4];
            float xs[4] = {x4.x, x4.y, x4.z, x4.w};
#pragma unroll
            for (int kk = 0; kk < 4; ++kk) {
                float xk = xs[kk];
                int k = 4 * k4 + kk;
#pragma unroll
                for (int j4 = 0; j4 < 16; ++j4) {
                    float4 w = sW[k * 16 + j4];
                    acc[4 * j4 + 0] = fmaf(xk, w.x, acc[4 * j4 + 0]);
                    acc[4 * j4 + 1] = fmaf(xk, w.y, acc[4 * j4 + 1]);
                    acc[4 * j4 + 2] = fmaf(xk, w.z, acc[4 * j4 + 2]);
                    acc[4 * j4 + 3] = fmaf(xk, w.w, acc[4 * j4 + 3]);
                }
            }
        }
        quant_store_u8(acc, qt + (size_t)row * 16, sc + row);
        return;
    }

    // ---- prep branch ----
    int e = (blockIdx.x - GEMM_BLOCKS) * 256 + threadIdx.x;
    if (e >= NE + 32) return;
    if (e >= NE) { erec[e] = 0u; return; }

    const int* p32 = (const int*)rowbuf;
    bool is64 = (p32[NE / 2 + 1] == 0 && p32[NE / 2] != 0);

    int r, rn, c;
    if (is64) {
        const long long* row = (const long long*)rowbuf;
        const long long* col = (const long long*)colbuf;
        r  = (int)row[e];
        rn = (e == NE - 1) ? NN : (int)row[e + 1];
        c  = (int)col[e];
    } else {
        const int* row = (const int*)rowbuf;
        const int* col = (const int*)colbuf;
        r  = row[e];
        rn = (e == NE - 1) ? NN : row[e + 1];
        c  = col[e];
    }
    erec[e] = ((bf16_rne(val[e]) & 0x7fffu) << 17) | (uint32)c;
    for (int q = r + 1; q <= rn; ++q) rp[q] = e + 1;
    if (e == 0) {
        for (int q = 0; q <= r; ++q) rp[q] = 0;
        ws[0]  = 0;
        ws[NW] = NN;
    }
    if (((e + 1) & (KE - 1)) == 0 && (e + 1) < NE)
        ws[(e + 1) / KE] = r + 1;
}

// ---------------------------------------------------------------------------
// SpMM on the biased-uint8 table. r16/r17 frame: 16-lane workers, exclusive
// row ownership, 16-deep gather pipeline, software-pipelined erec stream,
// no min-waves clause (r15: register squeeze -> scratch spill). Two r17
// fixes: (1) the shfl'd record is SAVED at ISSUE (U regs) and reused at
// ACCUM -- one ds_bpermute per edge instead of two; (2) unsigned-byte
// unpack: 4x v_cvt_f32_ubyte + one ts fma per edge, with the exact -128*ts
// correction at flush (r13-proven arithmetic). Lane sl holds features
// {4sl..4sl+3} = one uint of 4 bytes (64 B/row gather = one line per edge).
// Flush adds bias (+LeakyReLU+bf16-pack for layer 1; f32 float4 store for
// layer 2), each row stored exactly once. Overrun edges masked to record 0.
// ---------------------------------------------------------------------------
#define ISSUE(G, S, U, I) {                                     \
    U = (uint32)__shfl((int)rwm, (I), 16);                      \
    uint32 c_ = U & 0x1ffffu;                                   \
    G = qt[((size_t)c_ << 4) + (uint32)sl];                     \
    S = sc[c_]; }

#define FLUSH() {                                                       \
    float cr_ = -128.f * ts;                                            \
    float y0 = a0 + cr_ + bv.x, y1 = a1 + cr_ + bv.y,                   \
          y2 = a2 + cr_ + bv.z, y3 = a3 + cr_ + bv.w;                   \
    if (L1) {                                                           \
        y0 = (y0 >= 0.f) ? y0 : 0.2f * y0;                              \
        y1 = (y1 >= 0.f) ? y1 : 0.2f * y1;                              \
        y2 = (y2 >= 0.f) ? y2 : 0.2f * y2;                              \
        y3 = (y3 >= 0.f) ? y3 : 0.2f * y3;                              \
        uint2 pk_;                                                      \
        pk_.x = bf16_rne(y0) | (bf16_rne(y1) << 16);                    \
        pk_.y = bf16_rne(y2) | (bf16_rne(y3) << 16);                    \
        ((uint2*)obv)[(size_t)rr * 16 + sl] = pk_;                      \
    } else {                                                            \
        float4 f4_ = make_float4(y0, y1, y2, y3);                       \
        ((float4*)obv)[(size_t)rr * 16 + sl] = f4_;                     \
    }                                                                   \
    a0 = 0.f; a1 = 0.f; a2 = 0.f; a3 = 0.f; ts = 0.f; ++rr; }

#define ACCUM(G, S, U, I) {                                     \
    while (e0 + (I) >= re) {                                    \
        FLUSH();                                                \
        re = (rr < r1) ? rp[rr + 1] : 0x7fffffff;               \
    }                                                           \
    float t_ = __uint_as_float((U >> 17) << 16) * S;            \
    a0 = fmaf(t_, (float)(G & 0xffu),         a0);              \
    a1 = fmaf(t_, (float)((G >> 8) & 0xffu),  a1);              \
    a2 = fmaf(t_, (float)((G >> 16) & 0xffu), a2);              \
    a3 = fmaf(t_, (float)(G >> 24),           a3);              \
    ts += t_; }

template <bool L1>
__global__ __launch_bounds__(256) void spmm_kernel(
    const uint32* __restrict__ qt, const float* __restrict__ sc,
    const uint32* __restrict__ erec, const int* __restrict__ rp,
    const int* __restrict__ ws, const float* __restrict__ bias,
    void* __restrict__ obv) {
    int worker = (blockIdx.x * blockDim.x + threadIdx.x) >> 4;
    int sl = threadIdx.x & 15;
    if (worker >= NW) return;

    int rr = ws[worker];
    int r1 = ws[worker + 1];
    if (rr >= r1) return;

    const float4 bv = ((const float4*)bias)[sl];   // bias[4sl .. 4sl+3]

    int eb = rp[rr];
    int ee = rp[r1];
    int re = rp[rr + 1];
    float a0 = 0.f, a1 = 0.f, a2 = 0.f, a3 = 0.f, ts = 0.f;

    uint32 rwc = erec[eb + sl];              // batch-0 records (padded)
    for (int e0 = eb; e0 < ee; e0 += 16) {
        uint32 rwm = (e0 + sl < ee) ? rwc : 0u;   // mask overrun at use
        uint32 g0, g1, g2, g3, g4, g5, g6, g7;
        uint32 h0, h1, h2, h3, h4, h5, h6, h7;
        float  s0, s1, s2, s3, s4, s5, s6, s7;
        float  t0, t1, t2, t3, t4, t5, t6, t7;
        uint32 u0, u1, u2, u3, u4, u5, u6, u7;
        uint32 w0, w1, w2, w3, w4, w5, w6, w7;
        ISSUE(g0, s0, u0, 0)  ISSUE(g1, s1, u1, 1)
        ISSUE(g2, s2, u2, 2)  ISSUE(g3, s3, u3, 3)
        ISSUE(g4, s4, u4, 4)  ISSUE(g5, s5, u5, 5)
        ISSUE(g6, s6, u6, 6)  ISSUE(g7, s7, u7, 7)
        ISSUE(h0, t0, w0, 8)  ISSUE(h1, t1, w1, 9)
        ISSUE(h2, t2, w2, 10) ISSUE(h3, t3, w3, 11)
        ISSUE(h4, t4, w4, 12) ISSUE(h5, t5, w5, 13)
        ISSUE(h6, t6, w6, 14) ISSUE(h7, t7, w7, 15)
        rwc = erec[e0 + 16 + sl];            // prefetch next batch (padded:
                                             // e0+16+sl <= ee+30 <= NE+31)
        ACCUM(g0, s0, u0, 0)  ACCUM(g1, s1, u1, 1)
        ACCUM(g2, s2, u2, 2)  ACCUM(g3, s3, u3, 3)
        ACCUM(g4, s4, u4, 4)  ACCUM(g5, s5, u5, 5)
        ACCUM(g6, s6, u6, 6)  ACCUM(g7, s7, u7, 7)
        ACCUM(h0, t0, w0, 8)  ACCUM(h1, t1, w1, 9)
        ACCUM(h2, t2, w2, 10) ACCUM(h3, t3, w3, 11)
        ACCUM(h4, t4, w4, 12) ACCUM(h5, t5, w5, 13)
        ACCUM(h6, t6, w6, 14) ACCUM(h7, t7, w7, 15)
    }
    // drain: last row + trailing empty rows (bias-only rows handled too)
    while (rr < r1) { FLUSH(); }
}

// ---------------------------------------------------------------------------
// Dispatch 3: gemm2'  qt[row,:], sc[row] = quant_u8(unpack_bf16(h[row,:])@W2)
// (bias2 lives in spmm2's flush).
// ---------------------------------------------------------------------------
__global__ __launch_bounds__(256) void gemm_bb_kernel(
    const uint32* __restrict__ Bb, const float* __restrict__ W,
    uint32* __restrict__ qt, float* __restrict__ sc) {
    __shared__ float4 sW[DD * 16];
    for (int i = threadIdx.x; i < DD * 16; i += 256)
        sW[i] = ((const float4*)W)[i];
    __syncthreads();

    int row = blockIdx.x * 256 + threadIdx.x;
    if (row >= NN) return;

    float acc[DD];
#pragma unroll
    for (int j = 0; j < DD; ++j) acc[j] = 0.f;

    const uint4* Bp = (const uint4*)(Bb + (size_t)row * 32);
#pragma unroll
    for (int q4 = 0; q4 < 8; ++q4) {
        uint4 u4 = Bp[q4];
        uint32 us[4] = {u4.x, u4.y, u4.z, u4.w};
#pragma unroll
        for (int t = 0; t < 4; ++t) {
            int k = q4 * 8 + t * 2;
            float x0 = __uint_as_float(us[t] << 16);
            float x1 = __uint_as_float(us[t] & 0xffff0000u);
#pragma unroll
            for (int j4 = 0; j4 < 16; ++j4) {
                float4 w0 = sW[k * 16 + j4];
                float4 w1 = sW[(k + 1) * 16 + j4];
                acc[4 * j4 + 0] = fmaf(x0, w0.x, acc[4 * j4 + 0]);
                acc[4 * j4 + 1] = fmaf(x0, w0.y, acc[4 * j4 + 1]);
                acc[4 * j4 + 2] = fmaf(x0, w0.z, acc[4 * j4 + 2]);
                acc[4 * j4 + 3] = fmaf(x0, w0.w, acc[4 * j4 + 3]);
                acc[4 * j4 + 0] = fmaf(x1, w1.x, acc[4 * j4 + 0]);
                acc[4 * j4 + 1] = fmaf(x1, w1.y, acc[4 * j4 + 1]);
                acc[4 * j4 + 2] = fmaf(x1, w1.z, acc[4 * j4 + 2]);
                acc[4 * j4 + 3] = fmaf(x1, w1.w, acc[4 * j4 + 3]);
            }
        }
    }
    quant_store_u8(acc, qt + (size_t)row * 16, sc + row);
}

// ---------------------------------------------------------------------------
extern "C" void kernel_launch(void* const* d_in, const int* in_sizes, int n_in,
                              void* d_out, int out_size, void* d_ws, size_t ws_size,
                              hipStream_t stream) {
    const float* x       = (const float*)d_in[0];
    const void*  adj_row = d_in[1];
    const void*  adj_col = d_in[2];
    const float* adj_val = (const float*)d_in[3];
    const float* W1      = (const float*)d_in[4];
    const float* b1      = (const float*)d_in[5];
    const float* W2      = (const float*)d_in[6];
    const float* b2      = (const float*)d_in[7];
    float*       out     = (float*)d_out;

    // ws: bufA(h bf16) [NN*32 u32] | qt [NN*16 u32] | sc [NN f32] | erec | rp | ws
    uint32* bufA = (uint32*)d_ws;
    uint32* qt   = bufA + (size_t)NN * 32;
    float*  sc   = (float*)(qt + (size_t)NN * 16);
    uint32* erec = (uint32*)(sc + NN);
    int*    rp   = (int*)(erec + NE + 32);
    int*    wst  = rp + (NN + 1);

    const int spmm_blocks = (NW * 16) / 256;   // 3125

    // 1. prep || gemm1' : erec/rp/ws + qt,sc = quant_u8(x W1)
    pre_kernel<<<GEMM_BLOCKS + PREP_BLOCKS, 256, 0, stream>>>(
        adj_row, adj_col, adj_val, x, W1, erec, rp, wst, qt, sc);

    // 2. spmm1: bufA = bf16(LReLU(A dequant(qt) + b1))
    spmm_kernel<true><<<spmm_blocks, 256, 0, stream>>>(qt, sc, erec, rp, wst,
                                                       b1, bufA);

    // 3. gemm2': qt,sc = quant_u8(bufA W2)
    gemm_bb_kernel<<<GEMM_BLOCKS, 256, 0, stream>>>(bufA, W2, qt, sc);

    // 4. spmm2: out = A dequant(qt) + b2   (f32, float4 stores)
    spmm_kernel<false><<<spmm_blocks, 256, 0, stream>>>(qt, sc, erec, rp, wst,
                                                        b2, out);
}